// Round 7
// baseline (333.322 us; speedup 1.0000x reference)
//
#include <hip/hip_runtime.h>
#include <math.h>

#define HOP 512
#define N_HARM 5
#define PI_D 3.14159265358979323846

// float2-granular pad: +2 per 16 and +2 per 64 -> keeps 16B alignment of
// 4-aligned quads (P2(4m) even) while rotating banks between groups.
#define P2(a) ((a) + (((a) >> 4) << 1) + (((a) >> 6) << 1))

__device__ __forceinline__ float2 cadd(float2 a, float2 b) { return make_float2(a.x + b.x, a.y + b.y); }
__device__ __forceinline__ float2 csub(float2 a, float2 b) { return make_float2(a.x - b.x, a.y - b.y); }
__device__ __forceinline__ float2 cmul(float2 a, float2 b) {
    return make_float2(a.x * b.x - a.y * b.y, a.x * b.y + a.y * b.x);
}

// radix-4 DIF butterfly core (verified in rounds 5/6): u_q = sum_p x_p (-i)^{pq}
__device__ __forceinline__ void bfly4(float2 a, float2 b, float2 c, float2 d,
                                      float2& u0, float2& u1, float2& u2, float2& u3) {
    const float2 t0 = cadd(a, c), t1 = csub(a, c), t2 = cadd(b, d);
    const float2 t3 = make_float2(b.y - d.y, -(b.x - d.x));   // -i*(b-d)
    u0 = cadd(t0, t2); u1 = cadd(t1, t3);
    u2 = csub(t0, t2); u3 = csub(t1, t3);
}

// ---------------------------------------------------------------------------
// Setup: full-circle table tw2[k] = exp(-2*pi*i*k/2048), k in [0,2048), and
// periodic Hann window (2048), double precision.
// ---------------------------------------------------------------------------
__global__ void hfe_setup_tables(float2* __restrict__ tw2, float* __restrict__ win) {
    int i = blockIdx.x * blockDim.x + threadIdx.x;
    if (i < 2048) {
        double ang = -2.0 * PI_D * (double)i / 2048.0;
        tw2[i] = make_float2((float)cos(ang), (float)sin(ang));
        double c = cos(2.0 * PI_D * (double)i / 2048.0);
        win[i] = (float)(0.5 * (1.0 - c));
    }
}

// ---------------------------------------------------------------------------
// One in-place DIF radix-4 stage, stride S = 1<<LOG2S (S in {256,64,16}).
// Thread handles butterflies 4*lane .. 4*lane+3 (e-consecutive in one block),
// so each p-operand group is 4 contiguous float2 = 2 x float4 LDS accesses.
// Block length 4S; output y[base + e + qS] = u_q * W_{4S}^{e q},
// W_{4S} = W_2048^{512/S}  ->  exponent x1 = e << (9 - LOG2S).
// ---------------------------------------------------------------------------
template<int LOG2S>
__device__ __forceinline__ void dif_stage(float2* __restrict__ Z,
                                          const float2* __restrict__ tw2,
                                          const int lane) {
    constexpr int S = 1 << LOG2S;
    const int e0   = (4 * lane) & (S - 1);
    const int blk  = (4 * lane) >> LOG2S;
    const int base = (blk << (LOG2S + 2)) + e0;
    float2 v[4][4];                                     // [p][i], static idx only
    #pragma unroll
    for (int p = 0; p < 4; ++p) {
        const float4* src = reinterpret_cast<const float4*>(&Z[P2(base + p * S)]);
        const float4 lo = src[0], hi = src[1];
        v[p][0] = make_float2(lo.x, lo.y); v[p][1] = make_float2(lo.z, lo.w);
        v[p][2] = make_float2(hi.x, hi.y); v[p][3] = make_float2(hi.z, hi.w);
    }
    #pragma unroll
    for (int i = 0; i < 4; ++i) {
        float2 u0, u1, u2, u3;
        bfly4(v[0][i], v[1][i], v[2][i], v[3][i], u0, u1, u2, u3);
        const int x1 = (e0 + i) << (9 - LOG2S);         // < 512
        const float2 w1 = tw2[x1];
        const float2 w2 = tw2[(2 * x1) & 2047];
        const float2 w3 = tw2[(3 * x1) & 2047];
        v[0][i] = u0;
        v[1][i] = cmul(w1, u1);
        v[2][i] = cmul(w2, u2);
        v[3][i] = cmul(w3, u3);
    }
    #pragma unroll
    for (int p = 0; p < 4; ++p) {
        float4* dst = reinterpret_cast<float4*>(&Z[P2(base + p * S)]);
        dst[0] = make_float4(v[p][0].x, v[p][0].y, v[p][1].x, v[p][1].y);
        dst[1] = make_float4(v[p][2].x, v[p][2].y, v[p][3].x, v[p][3].y);
    }
}

// ---------------------------------------------------------------------------
// Merged S=4 and S=1 stages: thread's 16-block [16*lane, 16*lane+16) is
// self-contained for both. S=4: butterflies e on r[e+4p], twiddle W_16^{e q};
// S=1: butterflies on r[4b+p], twiddle-free.
// ---------------------------------------------------------------------------
__device__ __forceinline__ void dif_stage41(float2* __restrict__ Z,
                                            const float2* __restrict__ tw2,
                                            const int lane) {
    const int base = 16 * lane;
    float2 r[16];
    #pragma unroll
    for (int c = 0; c < 4; ++c) {
        const float4* src = reinterpret_cast<const float4*>(&Z[P2(base + 4 * c)]);
        const float4 lo = src[0], hi = src[1];
        r[4*c+0] = make_float2(lo.x, lo.y); r[4*c+1] = make_float2(lo.z, lo.w);
        r[4*c+2] = make_float2(hi.x, hi.y); r[4*c+3] = make_float2(hi.z, hi.w);
    }
    #pragma unroll
    for (int e = 0; e < 4; ++e) {
        float2 u0, u1, u2, u3;
        bfly4(r[e], r[e+4], r[e+8], r[e+12], u0, u1, u2, u3);
        const float2 w1 = tw2[128 * e];
        const float2 w2 = tw2[256 * e];
        const float2 w3 = tw2[384 * e];
        r[e]    = u0;
        r[e+4]  = cmul(w1, u1);
        r[e+8]  = cmul(w2, u2);
        r[e+12] = cmul(w3, u3);
    }
    #pragma unroll
    for (int b2 = 0; b2 < 4; ++b2) {
        float2 u0, u1, u2, u3;
        bfly4(r[4*b2], r[4*b2+1], r[4*b2+2], r[4*b2+3], u0, u1, u2, u3);
        r[4*b2] = u0; r[4*b2+1] = u1; r[4*b2+2] = u2; r[4*b2+3] = u3;
    }
    #pragma unroll
    for (int c = 0; c < 4; ++c) {
        float4* dst = reinterpret_cast<float4*>(&Z[P2(base + 4 * c)]);
        dst[0] = make_float4(r[4*c+0].x, r[4*c+0].y, r[4*c+1].x, r[4*c+1].y);
        dst[1] = make_float4(r[4*c+2].x, r[4*c+2].y, r[4*c+3].x, r[4*c+3].y);
    }
}

__device__ __forceinline__ int dr_hi(int lane6) {   // reverse 3 base-4 digits, <<4
    return ((lane6 & 3) << 8) | (((lane6 >> 2) & 3) << 6) | (((lane6 >> 4) & 3) << 4);
}

// ---------------------------------------------------------------------------
// 128-thread block = 2 frames, one 64-lane wave each.
//  1. load 2048 windowed samples (float4 fast path; reflect slow path) packed
//     z[n] = xw[2n] + i*xw[2n+1] into LDS natural order
//  2. in-place DIF: stages S=256,64,16, then merged S=4+1 (digit-rev output)
//  3. untwist pairs: one (Ze,Zo) gives |X[k]|^2 AND |X[1024-k]|^2
//  4. wave-only argmax (no LDS), mag table aliases Z, 5 harmonic gathers
// ---------------------------------------------------------------------------
__launch_bounds__(128)
__global__ void hfe_kernel(const float* __restrict__ audio,
                           const float2* __restrict__ tw2,
                           const float* __restrict__ win,
                           float* __restrict__ out,
                           int L, int T) {
    __shared__ float2 Zb[2][1184];                 // P2(1023)=1179 max
    const int lane = threadIdx.x & 63;
    const int fr   = threadIdx.x >> 6;
    float2* Z  = Zb[fr];
    float* mag = reinterpret_cast<float*>(Z);      // valid after untwist reads

    const int frame = blockIdx.x * 2 + fr;
    const int b     = frame / T;
    const int t     = frame - b * T;
    const long base = (long)b * (long)L;
    const int start = t * HOP - 1024;

    // ---- load: n = 16*lane + j, natural order
    if (start >= 0 && start + 2048 <= L) {
        const float4* a4 = reinterpret_cast<const float4*>(audio + base + start);
        const float4* w4 = reinterpret_cast<const float4*>(win);
        #pragma unroll
        for (int c = 0; c < 8; ++c) {
            const int q = lane * 8 + c;            // float4 id -> z[2q], z[2q+1]
            const float4 x = a4[q];
            const float4 w = w4[q];
            float4* dst = reinterpret_cast<float4*>(&Z[P2(2 * q)]);
            *dst = make_float4(x.x * w.x, x.y * w.y, x.z * w.z, x.w * w.w);
        }
    } else {
        #pragma unroll 4
        for (int j = 0; j < 16; ++j) {
            const int n = 16 * lane + j;
            const int i0 = 2 * n, i1 = 2 * n + 1;
            int p0 = start + i0;
            p0 = (p0 < 0) ? -p0 : p0;
            p0 = (p0 >= L) ? (2 * L - 2 - p0) : p0;
            int p1 = start + i1;
            p1 = (p1 < 0) ? -p1 : p1;
            p1 = (p1 >= L) ? (2 * L - 2 - p1) : p1;
            Z[P2(n)] = make_float2(audio[base + p0] * win[i0],
                                   audio[base + p1] * win[i1]);
        }
    }
    __syncthreads();

    dif_stage<8>(Z, tw2, lane);  __syncthreads();   // S=256
    dif_stage<6>(Z, tw2, lane);  __syncthreads();   // S=64
    dif_stage<4>(Z, tw2, lane);  __syncthreads();   // S=16
    dif_stage41(Z, tw2, lane);   __syncthreads();   // S=4 then S=1 (local)
    // Z now holds FFT(z) at digit-reversed positions dr(k)

    // ---- untwist pairs (k, 1024-k), k = lane + 64*j, j=0..7
    const int DRH  = dr_hi(lane);
    const int ln2  = (64 - lane) & 63;
    const int DRH2 = dr_hi(ln2);
    const bool l0  = (lane == 0);

    float m2a[8], m2b[8];
    float best = -1.0f;
    int   bidx = 0;
    #pragma unroll
    for (int j = 0; j < 8; ++j) {
        const int k   = lane + 64 * j;
        const int drl  = ((j & 3) << 2) | (j >> 2);
        const int ja   = 15 - j;
        const int jb   = (16 - j) & 15;
        const int drla = ((ja & 3) << 2) | (ja >> 2);
        const int drlb = ((jb & 3) << 2) | (jb >> 2);
        const float2 zk = Z[P2(DRH | drl)];
        const float2 zm = Z[P2(DRH2 | (l0 ? drlb : drla))];
        const float zer = 0.5f * (zk.x + zm.x), zei = 0.5f * (zk.y - zm.y);
        const float zor = 0.5f * (zk.y + zm.y), zoi = 0.5f * (zm.x - zk.x);
        const float2 w  = tw2[k];
        const float wr = w.x * zor - w.y * zoi;
        const float wi = w.x * zoi + w.y * zor;
        const float xpr = zer + wr, xpi = zei + wi;     // X[k]
        const float xmr = zer - wr, xmi = zei - wi;     // conj(X[1024-k])
        const float mp = xpr * xpr + xpi * xpi;
        const float mm = xmr * xmr + xmi * xmi;
        m2a[j] = mp; m2b[j] = mm;
        const int kb = 1024 - k;
        if (mp > best || (mp == best && k  < bidx)) { best = mp; bidx = k;  }
        if (mm > best || (mm == best && kb < bidx)) { best = mm; bidx = kb; }
    }
    float m512 = 0.0f;
    if (l0) {                                          // k=512, dr(512)=2
        const float2 z5 = Z[P2(2)];
        m512 = z5.x * z5.x + z5.y * z5.y;
        if (m512 > best || (m512 == best && 512 < bidx)) { best = m512; bidx = 512; }
    }

    // wave argmax reduce (tie -> lowest bin); single wave => no LDS needed
    #pragma unroll
    for (int off = 32; off > 0; off >>= 1) {
        const float ov = __shfl_xor(best, off);
        const int   oi = __shfl_xor(bidx, off);
        if (ov > best || (ov == best && oi < bidx)) { best = ov; bidx = oi; }
    }

    __syncthreads();                                   // all untwist reads done
    #pragma unroll
    for (int j = 0; j < 8; ++j) {
        mag[lane + 64 * j]        = m2a[j];
        mag[1024 - lane - 64 * j] = m2b[j];
    }
    if (l0) mag[512] = m512;
    __syncthreads();

    if (lane < N_HARM) {
        int bin = bidx * (lane + 1);
        if (bin > 1024) bin = 1024;
        const float e = sqrtf(mag[bin]);
        out[((long)b * N_HARM + lane) * (long)T + t] = log10f(e + 1e-10f);
    }
}

// ---------------------------------------------------------------------------
extern "C" void kernel_launch(void* const* d_in, const int* in_sizes, int n_in,
                              void* d_out, int out_size, void* d_ws, size_t ws_size,
                              hipStream_t stream) {
    const float* audio = (const float*)d_in[0];
    float*       out   = (float*)d_out;

    const int L = 655360;                 // samples per batch row (reference)
    const int B = in_sizes[0] / L;        // 32
    const int T = 1 + L / HOP;            // 1281 frames

    float2* tw2 = (float2*)d_ws;
    float*  win = (float*)((char*)d_ws + 2048 * sizeof(float2));

    hfe_setup_tables<<<8, 256, 0, stream>>>(tw2, win);
    hfe_kernel<<<(B * T) / 2, 128, 0, stream>>>(audio, tw2, win, out, L, T);
}

// Round 10
// 212.363 us; speedup vs baseline: 1.5696x; 1.5696x over previous
//
#include <hip/hip_runtime.h>
#include <math.h>

#define HOP 512
#define N_HARM 5
#define PI_D 3.14159265358979323846

// float2-index pad (r7-verified): +2 per 16 and +2 per 64 float2s.
// Keeps even indices even (16B alignment of float4 accesses) and rotates banks.
#define P2(a) ((a) + (((a) >> 4) << 1) + (((a) >> 6) << 1))

// ---------------------------------------------------------------------------
// Setup: full-circle table tw2[k] = exp(-2*pi*i*k/2048), and periodic Hann
// window (2048), double precision.
// ---------------------------------------------------------------------------
__global__ void hfe_setup_tables(float2* __restrict__ tw2, float* __restrict__ win) {
    int i = blockIdx.x * blockDim.x + threadIdx.x;
    if (i < 2048) {
        double ang = -2.0 * PI_D * (double)i / 2048.0;
        tw2[i] = make_float2((float)cos(ang), (float)sin(ang));
        double c = cos(2.0 * PI_D * (double)i / 2048.0);
        win[i] = (float)(0.5 * (1.0 - c));
    }
}

// Paired radix-4 DIF butterfly: (x,y)=frame A complex, (z,w)=frame B complex.
__device__ __forceinline__ void bfly4_pair(const float4 a, const float4 b,
                                           const float4 c, const float4 d,
                                           float4& u0, float4& u1,
                                           float4& u2, float4& u3) {
    float4 t0, t1, t2, t3;
    t0.x = a.x + c.x; t0.y = a.y + c.y; t0.z = a.z + c.z; t0.w = a.w + c.w;
    t1.x = a.x - c.x; t1.y = a.y - c.y; t1.z = a.z - c.z; t1.w = a.w - c.w;
    t2.x = b.x + d.x; t2.y = b.y + d.y; t2.z = b.z + d.z; t2.w = b.w + d.w;
    t3.x = b.y - d.y; t3.y = d.x - b.x;              // -i*(b-d), frame A
    t3.z = b.w - d.w; t3.w = d.z - b.z;              // -i*(b-d), frame B
    u0.x = t0.x + t2.x; u0.y = t0.y + t2.y; u0.z = t0.z + t2.z; u0.w = t0.w + t2.w;
    u1.x = t1.x + t3.x; u1.y = t1.y + t3.y; u1.z = t1.z + t3.z; u1.w = t1.w + t3.w;
    u2.x = t0.x - t2.x; u2.y = t0.y - t2.y; u2.z = t0.z - t2.z; u2.w = t0.w - t2.w;
    u3.x = t1.x - t3.x; u3.y = t1.y - t3.y; u3.z = t1.z - t3.z; u3.w = t1.w - t3.w;
}

__device__ __forceinline__ float4 cmul_pair(const float2 w, const float4 u) {
    return make_float4(w.x * u.x - w.y * u.y, w.x * u.y + w.y * u.x,
                       w.x * u.z - w.y * u.w, w.x * u.w + w.y * u.z);
}

// ---------------------------------------------------------------------------
// One in-place DIF radix-4 stage for the frame PAIR, stride S = 1<<LOG2S.
// Thread owns butterfly bf: operands/results at points base + p*S, which it
// alone reads and writes (no intra-stage cross-thread hazard).
// y[base+e+qS] = u_q * W_{4S}^{e q}; W_{4S}^e = tw2[e << (9-LOG2S)]  (r7-verified).
// ---------------------------------------------------------------------------
template<int LOG2S>
__device__ __forceinline__ void stage_pair(float2* __restrict__ Z,
                                           const float2* __restrict__ tw2,
                                           const int bf) {
    constexpr int S = 1 << LOG2S;
    const int e    = bf & (S - 1);
    const int blk  = bf >> LOG2S;
    const int base = (blk << (LOG2S + 2)) + e;
    float4 v0 = *reinterpret_cast<const float4*>(&Z[P2(2 * (base))]);
    float4 v1 = *reinterpret_cast<const float4*>(&Z[P2(2 * (base + S))]);
    float4 v2 = *reinterpret_cast<const float4*>(&Z[P2(2 * (base + 2 * S))]);
    float4 v3 = *reinterpret_cast<const float4*>(&Z[P2(2 * (base + 3 * S))]);
    float4 u0, u1, u2, u3;
    bfly4_pair(v0, v1, v2, v3, u0, u1, u2, u3);
    if constexpr (LOG2S > 0) {
        const int x1 = e << (9 - LOG2S);
        const float2 w1 = tw2[x1];
        const float2 w2 = tw2[(2 * x1) & 2047];
        const float2 w3 = tw2[(3 * x1) & 2047];
        u1 = cmul_pair(w1, u1);
        u2 = cmul_pair(w2, u2);
        u3 = cmul_pair(w3, u3);
    }
    *reinterpret_cast<float4*>(&Z[P2(2 * (base))])         = u0;
    *reinterpret_cast<float4*>(&Z[P2(2 * (base + S))])     = u1;
    *reinterpret_cast<float4*>(&Z[P2(2 * (base + 2 * S))]) = u2;
    *reinterpret_cast<float4*>(&Z[P2(2 * (base + 3 * S))]) = u3;
}

// reverse 5 base-4 digits of a 10-bit index (involution)
__device__ __forceinline__ int dr10(int k) {
    return ((k & 3) << 8) | (((k >> 2) & 3) << 6) | (((k >> 4) & 3) << 4)
         | (((k >> 6) & 3) << 2) | ((k >> 8) & 3);
}

// ---------------------------------------------------------------------------
// 256-thread block = 2 consecutive frames, interleaved in ONE LDS buffer:
// float2-index 2n   = frame A point n, 2n+1 = frame B point n (padded by P2).
//  1. load 2048 windowed samples per frame (shared window, float4 fast path)
//  2. in-place DIF radix-4, 5 stages S=256,64,16,4,1 -> digit-reversed output
//  3. untwist pairs (k,1024-k) for BOTH frames from 2 b128 reads
//  4. per-frame block argmax, mag table reuses Z, harmonic gathers
// ---------------------------------------------------------------------------
__launch_bounds__(256)
__global__ void hfe_kernel(const float* __restrict__ audio,
                           const float2* __restrict__ tw2,
                           const float* __restrict__ win,
                           float* __restrict__ out,
                           int L, int T) {
    __shared__ float2 Z[2368];                 // P2(2047)=2363 max
    __shared__ float wbA[4], wbB[4];
    __shared__ int   wiA[4], wiB[4];

    const int tid = threadIdx.x;
    const int fA  = blockIdx.x * 2, fB = fA + 1;
    const int bA  = fA / T, tA = fA - bA * T;
    const int bB  = fB / T, tB = fB - bB * T;
    const long baseA = (long)bA * (long)L;
    const long baseB = (long)bB * (long)L;
    const int startA = tA * HOP - 1024;
    const int startB = tB * HOP - 1024;

    // ---- load (window shared between the two frames)
    if (startA >= 0 && bA == bB && startB + 2048 <= L) {
        const float4* a4 = reinterpret_cast<const float4*>(audio + baseA + startA);
        const float4* w4 = reinterpret_cast<const float4*>(win);
        #pragma unroll
        for (int c = 0; c < 2; ++c) {
            const int q = tid + 256 * c;               // float4 id: points 2q,2q+1
            const float4 xA = a4[q];
            const float4 xB = a4[q + 128];             // frame B = A + 512 floats
            const float4 w  = w4[q];
            *reinterpret_cast<float4*>(&Z[P2(4 * q)]) =
                make_float4(xA.x * w.x, xA.y * w.y, xB.x * w.x, xB.y * w.y);
            *reinterpret_cast<float4*>(&Z[P2(4 * q + 2)]) =
                make_float4(xA.z * w.z, xA.w * w.w, xB.z * w.z, xB.w * w.w);
        }
    } else {
        for (int n = tid; n < 1024; n += 256) {
            const int i0 = 2 * n, i1 = 2 * n + 1;
            int p0 = startA + i0;
            p0 = (p0 < 0) ? -p0 : p0;
            p0 = (p0 >= L) ? (2 * L - 2 - p0) : p0;
            int p1 = startA + i1;
            p1 = (p1 < 0) ? -p1 : p1;
            p1 = (p1 >= L) ? (2 * L - 2 - p1) : p1;
            Z[P2(2 * n)] = make_float2(audio[baseA + p0] * win[i0],
                                       audio[baseA + p1] * win[i1]);
            int q0 = startB + i0;
            q0 = (q0 < 0) ? -q0 : q0;
            q0 = (q0 >= L) ? (2 * L - 2 - q0) : q0;
            int q1 = startB + i1;
            q1 = (q1 < 0) ? -q1 : q1;
            q1 = (q1 >= L) ? (2 * L - 2 - q1) : q1;
            Z[P2(2 * n) + 1] = make_float2(audio[baseB + q0] * win[i0],
                                           audio[baseB + q1] * win[i1]);
        }
    }
    __syncthreads();

    stage_pair<8>(Z, tw2, tid); __syncthreads();   // S=256
    stage_pair<6>(Z, tw2, tid); __syncthreads();   // S=64
    stage_pair<4>(Z, tw2, tid); __syncthreads();   // S=16
    stage_pair<2>(Z, tw2, tid); __syncthreads();   // S=4
    stage_pair<0>(Z, tw2, tid); __syncthreads();   // S=1 (twiddle-free)
    // X[k] (packed FFT) now at float2-index 2*dr10(k) (+1 for frame B)

    // ---- untwist pairs (k, 1024-k) for both frames
    float mv[2][4];                                // [j][mpA,mpB,mmA,mmB]
    float bestA = -1.0f, bestB = -1.0f;
    int   idxA = 0, idxB = 0;
    #pragma unroll
    for (int j = 0; j < 2; ++j) {
        const int k  = tid + 256 * j;              // 0..511
        const int km = (1024 - k) & 1023;
        const float4 zk = *reinterpret_cast<const float4*>(&Z[P2(2 * dr10(k))]);
        const float4 zm = *reinterpret_cast<const float4*>(&Z[P2(2 * dr10(km))]);
        const float2 w  = tw2[k];
        const int kb = 1024 - k;
        // frame A
        {
            const float zer = 0.5f * (zk.x + zm.x), zei = 0.5f * (zk.y - zm.y);
            const float zor = 0.5f * (zk.y + zm.y), zoi = 0.5f * (zm.x - zk.x);
            const float wr = w.x * zor - w.y * zoi;
            const float wi = w.x * zoi + w.y * zor;
            const float xpr = zer + wr, xpi = zei + wi;   // X[k]
            const float xmr = zer - wr, xmi = zei - wi;   // conj(X[1024-k])
            const float mp = xpr * xpr + xpi * xpi;
            const float mm = xmr * xmr + xmi * xmi;
            mv[j][0] = mp; mv[j][2] = mm;
            if (mp > bestA || (mp == bestA && k  < idxA)) { bestA = mp; idxA = k;  }
            if (mm > bestA || (mm == bestA && kb < idxA)) { bestA = mm; idxA = kb; }
        }
        // frame B
        {
            const float zer = 0.5f * (zk.z + zm.z), zei = 0.5f * (zk.w - zm.w);
            const float zor = 0.5f * (zk.w + zm.w), zoi = 0.5f * (zm.z - zk.z);
            const float wr = w.x * zor - w.y * zoi;
            const float wi = w.x * zoi + w.y * zor;
            const float xpr = zer + wr, xpi = zei + wi;
            const float xmr = zer - wr, xmi = zei - wi;
            const float mp = xpr * xpr + xpi * xpi;
            const float mm = xmr * xmr + xmi * xmi;
            mv[j][1] = mp; mv[j][3] = mm;
            if (mp > bestB || (mp == bestB && k  < idxB)) { bestB = mp; idxB = k;  }
            if (mm > bestB || (mm == bestB && kb < idxB)) { bestB = mm; idxB = kb; }
        }
    }
    float m512A = 0.0f, m512B = 0.0f;
    if (tid == 0) {                                // k=512, dr10(512)=2
        const float4 z5 = *reinterpret_cast<const float4*>(&Z[P2(4)]);
        m512A = z5.x * z5.x + z5.y * z5.y;
        m512B = z5.z * z5.z + z5.w * z5.w;
        if (m512A > bestA || (m512A == bestA && 512 < idxA)) { bestA = m512A; idxA = 512; }
        if (m512B > bestB || (m512B == bestB && 512 < idxB)) { bestB = m512B; idxB = 512; }
    }

    // wave argmax reduce, both frames (tie -> lowest bin)
    #pragma unroll
    for (int off = 32; off > 0; off >>= 1) {
        float ov = __shfl_xor(bestA, off);
        int   oi = __shfl_xor(idxA, off);
        if (ov > bestA || (ov == bestA && oi < idxA)) { bestA = ov; idxA = oi; }
        ov = __shfl_xor(bestB, off);
        oi = __shfl_xor(idxB, off);
        if (ov > bestB || (ov == bestB && oi < idxB)) { bestB = ov; idxB = oi; }
    }
    const int wv = tid >> 6;
    if ((tid & 63) == 0) { wbA[wv] = bestA; wiA[wv] = idxA; wbB[wv] = bestB; wiB[wv] = idxB; }
    __syncthreads();                               // all Z reads complete

    // mag table (float2: .x = frame A, .y = frame B) reuses Z, raw indices
    float2* magv = Z;
    #pragma unroll
    for (int j = 0; j < 2; ++j) {
        const int k = tid + 256 * j;
        magv[k]        = make_float2(mv[j][0], mv[j][1]);
        magv[1024 - k] = make_float2(mv[j][2], mv[j][3]);
    }
    if (tid == 0) magv[512] = make_float2(m512A, m512B);
    __syncthreads();

    if (tid < N_HARM) {
        float bb = wbA[0]; int bx = wiA[0];
        #pragma unroll
        for (int w = 1; w < 4; ++w)
            if (wbA[w] > bb || (wbA[w] == bb && wiA[w] < bx)) { bb = wbA[w]; bx = wiA[w]; }
        int bin = bx * (tid + 1);
        if (bin > 1024) bin = 1024;
        const float e = sqrtf(magv[bin].x);
        out[((long)bA * N_HARM + tid) * (long)T + tA] = log10f(e + 1e-10f);
    } else if (tid >= 64 && tid < 64 + N_HARM) {
        const int h = tid - 64;
        float bb = wbB[0]; int bx = wiB[0];
        #pragma unroll
        for (int w = 1; w < 4; ++w)
            if (wbB[w] > bb || (wbB[w] == bb && wiB[w] < bx)) { bb = wbB[w]; bx = wiB[w]; }
        int bin = bx * (h + 1);
        if (bin > 1024) bin = 1024;
        const float e = sqrtf(magv[bin].y);
        out[((long)bB * N_HARM + h) * (long)T + tB] = log10f(e + 1e-10f);
    }
}

// ---------------------------------------------------------------------------
extern "C" void kernel_launch(void* const* d_in, const int* in_sizes, int n_in,
                              void* d_out, int out_size, void* d_ws, size_t ws_size,
                              hipStream_t stream) {
    const float* audio = (const float*)d_in[0];
    float*       out   = (float*)d_out;

    const int L = 655360;                 // samples per batch row (reference)
    const int B = in_sizes[0] / L;        // 32
    const int T = 1 + L / HOP;            // 1281 frames

    float2* tw2 = (float2*)d_ws;
    float*  win = (float*)((char*)d_ws + 2048 * sizeof(float2));

    hfe_setup_tables<<<8, 256, 0, stream>>>(tw2, win);
    hfe_kernel<<<(B * T) / 2, 256, 0, stream>>>(audio, tw2, win, out, L, T);
}